// Round 3
// baseline (25701.520 us; speedup 1.0000x reference)
//
#include <hip/hip_runtime.h>
#include <hip/hip_bf16.h>
#include <stdint.h>

typedef unsigned int uint;
typedef unsigned long long u64;

#define T_STEPS 128
#define BQ 16
#define HID 512
#define NSLOT 1024
#define MD 64
#define VOCAB 32000
#define BETA 1.000001f
#define EPSN 1e-8f

__device__ __forceinline__ float sigm(float x){ return 1.f/(1.f+expf(-x)); }

// pack (score, slot) so that u64 max == (max value, min slot on ties) — matches lax.top_k
__device__ __forceinline__ u64 packsc(float v, int slot){
  uint u = __float_as_uint(v);
  u = (u & 0x80000000u) ? ~u : (u | 0x80000000u);
  return ((u64)u << 10) | (u64)(1023 - slot);
}
__device__ __forceinline__ float unpackval(u64 p){
  uint u = (uint)(p >> 10);
  uint bits = (u & 0x80000000u) ? (u & 0x7fffffffu) : ~u;
  return __uint_as_float(bits);
}
__device__ __forceinline__ int unpackslot(u64 p){ return 1023 - (int)(p & 1023u); }

// ---------------- phase 0a: embedding gather ----------------
__global__ __launch_bounds__(256) void prep_emb(const float* __restrict__ E,
                                                const int* __restrict__ seq,
                                                float* __restrict__ EMB){
  int m = blockIdx.x;              // m = t*16 + b
  int t = m >> 4, b = m & 15;
  int x = seq[b*T_STEPS + t];
  EMB[(size_t)m*256 + threadIdx.x] = E[(size_t)x*256 + threadIdx.x];
}

// ---------------- phase 0b: G_emb[m][r] = EMB[m] . W_ih[r][0:256] + b_ih[r]+b_hh[r] ----
__global__ __launch_bounds__(256) void gemm_emb(const float* __restrict__ A,
                                                const float* __restrict__ W_ih,
                                                const float* __restrict__ b_ih,
                                                const float* __restrict__ b_hh,
                                                float* __restrict__ C){
  __shared__ __align__(16) float As[16*68];
  __shared__ __align__(16) float Bs[16*68];
  int mt = blockIdx.x & 31, nt = blockIdx.x >> 5;
  int m0 = mt*64, n0 = nt*64;
  int tx = threadIdx.x & 15, ty = threadIdx.x >> 4;
  float acc[4][4] = {};
  for (int k0 = 0; k0 < 256; k0 += 16){
    int mm = threadIdx.x >> 2, kq = (threadIdx.x & 3)*4;
    float4 a = *(const float4*)(A + (size_t)(m0+mm)*256 + k0 + kq);
    As[(kq+0)*68+mm]=a.x; As[(kq+1)*68+mm]=a.y; As[(kq+2)*68+mm]=a.z; As[(kq+3)*68+mm]=a.w;
    int r = n0 + mm;
    float4 bv = *(const float4*)(W_ih + (size_t)r*320 + k0 + kq);
    Bs[(kq+0)*68+mm]=bv.x; Bs[(kq+1)*68+mm]=bv.y; Bs[(kq+2)*68+mm]=bv.z; Bs[(kq+3)*68+mm]=bv.w;
    __syncthreads();
    #pragma unroll
    for (int kk = 0; kk < 16; ++kk){
      float4 av = *(const float4*)(As + kk*68 + ty*4);
      float4 bb = *(const float4*)(Bs + kk*68 + tx*4);
      float aa[4] = {av.x,av.y,av.z,av.w};
      float bv2[4] = {bb.x,bb.y,bb.z,bb.w};
      #pragma unroll
      for (int i = 0; i < 4; ++i)
        #pragma unroll
        for (int j = 0; j < 4; ++j)
          acc[i][j] = fmaf(aa[i], bv2[j], acc[i][j]);
    }
    __syncthreads();
  }
  #pragma unroll
  for (int i = 0; i < 4; ++i){
    int m = m0 + ty*4 + i;
    #pragma unroll
    for (int j = 0; j < 4; ++j){
      int r = n0 + tx*4 + j;
      C[(size_t)m*2048 + r] = acc[i][j] + b_ih[r] + b_hh[r];
    }
  }
}

// ---------------- tiled transpose: out[k][r] = in[r][koff + k] ----------------
// grid: (K/32, R/32), block 256
__global__ __launch_bounds__(256) void transpose_w(const float* __restrict__ in,
                                                   float* __restrict__ out,
                                                   int R, int istride, int koff){
  __shared__ float tl[32][33];
  int k0 = blockIdx.x*32, r0 = blockIdx.y*32;
  int tx = threadIdx.x & 31, ty = threadIdx.x >> 5;   // 32 x 8
  #pragma unroll
  for (int i = 0; i < 4; ++i)
    tl[ty + i*8][tx] = in[(size_t)(r0 + ty + i*8)*istride + koff + k0 + tx];
  __syncthreads();
  #pragma unroll
  for (int i = 0; i < 4; ++i)
    out[(size_t)(k0 + ty + i*8)*R + r0 + tx] = tl[tx][ty + i*8];
}

// ---------------- the recurrence: ONE workgroup per batch, zero grid sync ----------------
// LDS float offsets
#define L_H     0        // h_s[512]
#define L_RV    512      // rv_s[64]
#define L_GL    576      // gl[2048]
#define L_PROJ  2624     // proj_s[1024]  (rk|wk|wv|er, 4x256)
#define L_KEYT  3648     // keyT[64][8]
#define L_WGT   4160     // wgt[64]
#define L_SLOT  4224     // slotl[64] (int)
#define L_RVP   4288     // rvp[16][64]
#define L_CND   5312     // cnd: 16 lists x 8 u64 (256 floats)
#define L_SC8   5568     // sc8: 8 x 1032 u64 (16512 floats)
#define L_TOT   22080    // 88320 bytes

__global__ __launch_bounds__(1024, 1) void recurrent_batch(
    const float* __restrict__ W_hhT,    // [512][2048]
    const float* __restrict__ W_ihrvT,  // [64][2048]
    const float* __restrict__ W_rk, const float* __restrict__ b_rk,
    const float* __restrict__ W_wk, const float* __restrict__ b_wk,
    const float* __restrict__ W_wv, const float* __restrict__ b_wv,
    const float* __restrict__ W_er, const float* __restrict__ b_er,
    const float* __restrict__ G_emb,    // [2048][2048]
    float* __restrict__ H_all,          // [2048][512]
    float* __restrict__ memT_g)         // [16][64][1024] transposed memory
{
  __shared__ __align__(16) float smem[L_TOT];
  float* h_s    = smem + L_H;
  float* rv_s   = smem + L_RV;
  float* gl     = smem + L_GL;
  float* proj_s = smem + L_PROJ;
  float* keyT   = smem + L_KEYT;
  float* wgt    = smem + L_WGT;
  int*   slotl  = (int*)(smem + L_SLOT);
  float* rvp    = smem + L_RVP;
  u64*   cnd    = (u64*)(smem + L_CND);
  u64*   sc8    = (u64*)(smem + L_SC8);

  const int tid = threadIdx.x;
  const int bb  = blockIdx.x;
  float* memT = memT_g + (size_t)bb*MD*NSLOT;

  // ---- init ----
  if (tid < 512) h_s[tid] = 0.f;
  if (tid < 64)  rv_s[tid] = 0.f;
  float c_reg = 0.f;
  #pragma unroll 4
  for (int d = 0; d < MD; ++d) memT[d*NSLOT + tid] = 1e-6f;   // coalesced

  // gates constants: thread computes packed gate rows r0, r0+1
  const int gj = tid & 511, ghalf = tid >> 9;
  const int r0 = ghalf*1024 + gj*2;
  const float* whp = W_hhT + r0;
  const float* wrp = W_ihrvT + r0;
  // proj constants: thread computes proj output (msel, pl)
  const int msel = tid >> 8, pl = tid & 255;
  const float* Wm  = (msel==0)? W_rk : (msel==1)? W_wk : (msel==2)? W_wv : W_er;
  const float* bmp = (msel==0)? b_rk : (msel==1)? b_wk : (msel==2)? b_wv : b_er;
  const float pbias = bmp[pl];
  const float* Wmp = Wm + pl;
  // top8 constants
  const int wv_  = tid >> 6, lane = tid & 63;
  const int thh  = wv_ >> 1, tqh = wv_ & 1;
  __syncthreads();

  #pragma clang loop unroll(disable)
  for (int t = 0; t < T_STEPS; ++t){
    // ======== S0: gates = G_emb + h@W_hh + rv@W_rv ========
    {
      const float2 g2 = *(const float2*)(G_emb + (size_t)(t*BQ + bb)*2048 + r0);
      float a0 = g2.x, a1 = g2.y, b0 = 0.f, b1 = 0.f;
      #pragma unroll 2
      for (int k = 0; k < 512; k += 4){
        float4 hv = *(const float4*)(h_s + k);
        float2 w0 = *(const float2*)(whp + (size_t)(k+0)*2048);
        float2 w1 = *(const float2*)(whp + (size_t)(k+1)*2048);
        float2 w2 = *(const float2*)(whp + (size_t)(k+2)*2048);
        float2 w3 = *(const float2*)(whp + (size_t)(k+3)*2048);
        a0 = fmaf(hv.x, w0.x, a0); a1 = fmaf(hv.x, w0.y, a1);
        b0 = fmaf(hv.y, w1.x, b0); b1 = fmaf(hv.y, w1.y, b1);
        a0 = fmaf(hv.z, w2.x, a0); a1 = fmaf(hv.z, w2.y, a1);
        b0 = fmaf(hv.w, w3.x, b0); b1 = fmaf(hv.w, w3.y, b1);
      }
      #pragma unroll
      for (int k = 0; k < 64; k += 4){
        float4 rvv = *(const float4*)(rv_s + k);
        float2 w0 = *(const float2*)(wrp + (size_t)(k+0)*2048);
        float2 w1 = *(const float2*)(wrp + (size_t)(k+1)*2048);
        float2 w2 = *(const float2*)(wrp + (size_t)(k+2)*2048);
        float2 w3 = *(const float2*)(wrp + (size_t)(k+3)*2048);
        a0 = fmaf(rvv.x, w0.x, a0); a1 = fmaf(rvv.x, w0.y, a1);
        b0 = fmaf(rvv.y, w1.x, b0); b1 = fmaf(rvv.y, w1.y, b1);
        a0 = fmaf(rvv.z, w2.x, a0); a1 = fmaf(rvv.z, w2.y, a1);
        b0 = fmaf(rvv.w, w3.x, b0); b1 = fmaf(rvv.w, w3.y, b1);
      }
      float2 o; o.x = a0 + b0; o.y = a1 + b1;
      *(float2*)(gl + r0) = o;
    }
    __syncthreads();
    // ======== S1: LSTM elementwise ========
    if (tid < 512){
      float gi = gl[tid], gf = gl[512+tid], gg = gl[1024+tid], go = gl[1536+tid];
      c_reg = sigm(gf)*c_reg + sigm(gi)*tanhf(gg);
      float h = sigm(go)*tanhf(c_reg);
      h_s[tid] = h;
      H_all[(size_t)(t*BQ + bb)*HID + tid] = h;
    }
    __syncthreads();
    // ======== S2: projections rk|wk|wv|er (+ keyT mirror) ========
    {
      float acc0 = 0.f, acc1 = 0.f;
      #pragma unroll 2
      for (int k = 0; k < 512; k += 4){
        float4 hv = *(const float4*)(h_s + k);
        acc0 = fmaf(hv.x, Wmp[(size_t)(k+0)*256], acc0);
        acc1 = fmaf(hv.y, Wmp[(size_t)(k+1)*256], acc1);
        acc0 = fmaf(hv.z, Wmp[(size_t)(k+2)*256], acc0);
        acc1 = fmaf(hv.w, Wmp[(size_t)(k+3)*256], acc1);
      }
      float v = acc0 + acc1 + pbias;
      if (msel == 3) v = sigm(v);
      proj_s[tid] = v;
      if (msel < 2) keyT[(pl & 63)*8 + msel*4 + (pl >> 6)] = v;  // keyT[d][key]
    }
    __syncthreads();
    // ======== S4: scores for all 8 keys vs own slot (slot = tid) ========
    {
      float ss = 0.f;
      float dk0=0,dk1=0,dk2=0,dk3=0,dk4=0,dk5=0,dk6=0,dk7=0;
      #pragma unroll 4
      for (int d = 0; d < MD; ++d){
        float m = memT[d*NSLOT + tid];
        float4 k0 = *(const float4*)(keyT + d*8);
        float4 k1 = *(const float4*)(keyT + d*8 + 4);
        ss  = fmaf(m, m, ss);
        dk0 = fmaf(m, k0.x, dk0); dk1 = fmaf(m, k0.y, dk1);
        dk2 = fmaf(m, k0.z, dk2); dk3 = fmaf(m, k0.w, dk3);
        dk4 = fmaf(m, k1.x, dk4); dk5 = fmaf(m, k1.y, dk5);
        dk6 = fmaf(m, k1.z, dk6); dk7 = fmaf(m, k1.w, dk7);
      }
      float rnm = BETA / (sqrtf(ss) + EPSN);   // key-norm folded in at merge (order-invariant)
      sc8[0*1032 + tid] = packsc(dk0*rnm, tid);
      sc8[1*1032 + tid] = packsc(dk1*rnm, tid);
      sc8[2*1032 + tid] = packsc(dk2*rnm, tid);
      sc8[3*1032 + tid] = packsc(dk3*rnm, tid);
      sc8[4*1032 + tid] = packsc(dk4*rnm, tid);
      sc8[5*1032 + tid] = packsc(dk5*rnm, tid);
      sc8[6*1032 + tid] = packsc(dk6*rnm, tid);
      sc8[7*1032 + tid] = packsc(dk7*rnm, tid);
    }
    __syncthreads();
    // ======== S5: per-wave top8 (wave w: head w>>1, half w&1 -> 512 slots) ========
    {
      const u64* src = sc8 + thh*1032 + tqh*512 + lane;
      u64 p0 = src[0*64], p1 = src[1*64], p2 = src[2*64], p3 = src[3*64];
      u64 p4 = src[4*64], p5 = src[5*64], p6 = src[6*64], p7 = src[7*64];
      #pragma unroll
      for (int r = 0; r < 8; ++r){
        u64 m01 = p0 > p1 ? p0 : p1;
        u64 m23 = p2 > p3 ? p2 : p3;
        u64 m45 = p4 > p5 ? p4 : p5;
        u64 m67 = p6 > p7 ? p6 : p7;
        u64 m03 = m01 > m23 ? m01 : m23;
        u64 m47 = m45 > m67 ? m45 : m67;
        u64 m = m03 > m47 ? m03 : m47;
        #pragma unroll
        for (int o = 32; o; o >>= 1){ u64 q = __shfl_xor(m, o); if (q > m) m = q; }
        if (p0 == m) p0 = 0; if (p1 == m) p1 = 0;
        if (p2 == m) p2 = 0; if (p3 == m) p3 = 0;
        if (p4 == m) p4 = 0; if (p5 == m) p5 = 0;
        if (p6 == m) p6 = 0; if (p7 == m) p7 = 0;
        if (lane == 0) cnd[(thh*2 + tqh)*8 + r] = m;
      }
    }
    __syncthreads();
    // ======== S6: merge two sorted 8-lists per head + softmax (8 threads) ========
    if (tid < 8){
      const int hh = tid;
      float kn = 0.f;
      #pragma unroll 8
      for (int d = 0; d < MD; ++d){ float kv = keyT[d*8 + hh]; kn = fmaf(kv, kv, kn); }
      float rkn = 1.f / (sqrtf(kn) + EPSN);
      int i0 = 0, i1 = 0;
      float vals[8]; int sl[8];
      #pragma unroll
      for (int r = 0; r < 8; ++r){
        u64 a = cnd[(hh*2+0)*8 + i0];
        u64 b = cnd[(hh*2+1)*8 + i1];
        u64 m; if (a > b){ m = a; ++i0; } else { m = b; ++i1; }
        vals[r] = unpackval(m) * rkn;
        sl[r]   = unpackslot(m);
      }
      float vm = vals[0];
      float et[8], sum = 0.f;
      #pragma unroll
      for (int r = 0; r < 8; ++r){ et[r] = expf(vals[r] - vm); sum += et[r]; }
      float rs = 1.f / sum;
      #pragma unroll
      for (int r = 0; r < 8; ++r){ wgt[hh*8 + r] = et[r]*rs; slotl[hh*8 + r] = sl[r]; }
    }
    __syncthreads();
    // ======== S7: read-vector partials (read heads 0..3, memory pre-write) ========
    {
      const int hh = tid >> 8;          // 0..3
      const int rr = (tid >> 6) & 3;
      const int d  = tid & 63;
      float w0 = wgt[hh*8 + rr],   w1 = wgt[hh*8 + rr + 4];
      int   s0 = slotl[hh*8 + rr], s1 = slotl[hh*8 + rr + 4];
      rvp[(hh*4 + rr)*64 + d] = w0*memT[d*NSLOT + s0] + w1*memT[d*NSLOT + s1];
    }
    __syncthreads();
    // ======== S8: rv finalize + sparse erase/add memory update ========
    if (tid < 64){
      float s = 0.f;
      #pragma unroll
      for (int i = 0; i < 16; ++i) s += rvp[i*64 + tid];
      rv_s[tid] = 0.25f * s;
    }
    {
      uint mask = 0;
      #pragma unroll
      for (int e = 0; e < 32; ++e)
        mask |= (slotl[32 + e] == tid) ? (1u << e) : 0u;
      if (mask){
        #pragma unroll 4
        for (int d = 0; d < MD; ++d){
          float v = memT[d*NSLOT + tid];
          float keep = 1.f, add = 0.f;
          uint mk = mask;
          while (mk){
            int e = __builtin_ctz(mk); mk &= mk - 1;
            float w = wgt[32 + e]; int hh = e >> 3;
            keep *= 1.f - w*proj_s[768 + hh*64 + d];   // er
            add  += w*proj_s[512 + hh*64 + d];          // wv
          }
          memT[d*NSLOT + tid] = v*keep + add;
        }
      }
    }
    __syncthreads();
  }
}

// ---------------- phase B: logits = H_all[2048,512] @ W_out[512,32000] + b_out ----------------
__global__ __launch_bounds__(256) void gemm_out(const float* __restrict__ A,
                                                const float* __restrict__ Bmat,
                                                const float* __restrict__ bias,
                                                float* __restrict__ C){
  __shared__ __align__(16) float As[16*132];
  __shared__ __align__(16) float Bs[16*64];
  int mt = blockIdx.x & 15, nt = blockIdx.x >> 4;
  int m0 = mt*128, n0 = nt*64;
  int tx = threadIdx.x & 15, ty = threadIdx.x >> 4;
  float acc[8][4] = {};
  for (int k0 = 0; k0 < 512; k0 += 16){
    int mm = threadIdx.x >> 1, kq = (threadIdx.x & 1)*8;
    float4 a0 = *(const float4*)(A + (size_t)(m0+mm)*512 + k0 + kq);
    float4 a1 = *(const float4*)(A + (size_t)(m0+mm)*512 + k0 + kq + 4);
    As[(kq+0)*132+mm]=a0.x; As[(kq+1)*132+mm]=a0.y; As[(kq+2)*132+mm]=a0.z; As[(kq+3)*132+mm]=a0.w;
    As[(kq+4)*132+mm]=a1.x; As[(kq+5)*132+mm]=a1.y; As[(kq+6)*132+mm]=a1.z; As[(kq+7)*132+mm]=a1.w;
    int kk2 = threadIdx.x >> 4, nq = (threadIdx.x & 15)*4;
    *(float4*)(Bs + kk2*64 + nq) = *(const float4*)(Bmat + (size_t)(k0+kk2)*VOCAB + n0 + nq);
    __syncthreads();
    #pragma unroll
    for (int kk = 0; kk < 16; ++kk){
      float4 x0 = *(const float4*)(As + kk*132 + ty*8);
      float4 x1 = *(const float4*)(As + kk*132 + ty*8 + 4);
      float4 bv = *(const float4*)(Bs + kk*64 + tx*4);
      float aa[8] = {x0.x,x0.y,x0.z,x0.w,x1.x,x1.y,x1.z,x1.w};
      float bb[4] = {bv.x,bv.y,bv.z,bv.w};
      #pragma unroll
      for (int i = 0; i < 8; ++i)
        #pragma unroll
        for (int j = 0; j < 4; ++j)
          acc[i][j] = fmaf(aa[i], bb[j], acc[i][j]);
    }
    __syncthreads();
  }
  #pragma unroll
  for (int i = 0; i < 8; ++i){
    int m = m0 + ty*8 + i;
    int bq = m & 15, tt = m >> 4;
    float* crow = C + ((size_t)bq*T_STEPS + tt)*VOCAB + n0 + tx*4;
    #pragma unroll
    for (int j = 0; j < 4; ++j) crow[j] = acc[i][j] + bias[n0 + tx*4 + j];
  }
}

extern "C" void kernel_launch(void* const* d_in, const int* in_sizes, int n_in,
                              void* d_out, int out_size, void* d_ws, size_t ws_size,
                              hipStream_t stream){
  const int*   seq   = (const int*)d_in[0];
  const float* E     = (const float*)d_in[1];
  const float* W_ih  = (const float*)d_in[2];
  const float* W_hh  = (const float*)d_in[3];
  const float* b_ih  = (const float*)d_in[4];
  const float* b_hh  = (const float*)d_in[5];
  const float* W_out = (const float*)d_in[6];
  const float* b_out = (const float*)d_in[7];
  const float* W_rk  = (const float*)d_in[8];
  const float* b_rk  = (const float*)d_in[9];
  const float* W_wk  = (const float*)d_in[10];
  const float* b_wk  = (const float*)d_in[11];
  const float* W_wv  = (const float*)d_in[12];
  const float* b_wv  = (const float*)d_in[13];
  const float* W_er  = (const float*)d_in[14];
  const float* b_er  = (const float*)d_in[15];
  float* out = (float*)d_out;
  (void)in_sizes; (void)n_in; (void)out_size; (void)ws_size;

  char* ws = (char*)d_ws;
  size_t off = 0;
  auto alloc = [&](size_t bytes) -> void* {
    off = (off + 255) & ~(size_t)255;
    void* p = ws + off;
    off += bytes;
    return p;
  };
  float* EMB     = (float*)alloc((size_t)2048*256*4);
  float* G_emb   = (float*)alloc((size_t)2048*2048*4);
  float* H_all   = (float*)alloc((size_t)2048*512*4);
  float* memT    = (float*)alloc((size_t)16*64*1024*4);
  float* W_hhT   = (float*)alloc((size_t)512*2048*4);
  float* W_ihrvT = (float*)alloc((size_t)64*2048*4);

  prep_emb<<<2048, 256, 0, stream>>>(E, seq, EMB);
  gemm_emb<<<1024, 256, 0, stream>>>(EMB, W_ih, b_ih, b_hh, G_emb);
  transpose_w<<<dim3(16,64), 256, 0, stream>>>(W_hh, W_hhT, 2048, 512, 0);
  transpose_w<<<dim3(2,64),  256, 0, stream>>>(W_ih, W_ihrvT, 2048, 320, 256);
  recurrent_batch<<<16, 1024, 0, stream>>>(W_hhT, W_ihrvT,
                                           W_rk, b_rk, W_wk, b_wk,
                                           W_wv, b_wv, W_er, b_er,
                                           G_emb, H_all, memT);
  gemm_out<<<16*500, 256, 0, stream>>>(H_all, W_out, b_out, out);
}

// Round 4
// 7367.842 us; speedup vs baseline: 3.4883x; 3.4883x over previous
//
#include <hip/hip_runtime.h>
#include <hip/hip_bf16.h>
#include <stdint.h>

typedef unsigned int uint;
typedef unsigned long long u64;

#define T_STEPS 128
#define BQ 16
#define HID 512
#define NSLOT 1024
#define MD 64
#define VOCAB 32000
#define NWG 128
#define BETA 1.000001f
#define EPSN 1e-8f

// LDS float offsets (all regions statically disjoint; 98.5 KB total)
#define L_MEM  0        // mem_s[128][68] persistent
#define L_NRM  8704     // nrm_s[128] persistent
#define L_WS   8832     // Ws[8][516] persistent proj-weight slice
#define L_HS   12960    // hs[16][516] staged h_t
#define L_KEY  21216    // key_s[512]
#define L_KNRM 21728    // knrm_s[8]
#define L_SC   21736    // sc_s[8][128]
#define L_WV   22760    // wv_s[256]
#define L_ER   23016    // er_s[256]
#define L_WL   23272    // wl_s[32] u64 (64 floats)
#define L_GL   23336    // gl[256]
#define L_RV   23592    // rv_st[1024]
#define L_TOT  24616

// agent-coherent loads (bypass L1/L2); batched waitcnt (+sched_barrier, rule #18)
#define AL4(dst, p) asm volatile("global_load_dwordx4 %0, %1, off sc0 sc1" : "=v"(dst) : "v"(p))
#define ALF(dst, p) asm volatile("global_load_dword %0, %1, off sc0 sc1" : "=v"(dst) : "v"(p))
#define AWAIT() do { asm volatile("s_waitcnt vmcnt(0)" ::: "memory"); __builtin_amdgcn_sched_barrier(0); } while(0)

__device__ __forceinline__ float sigm(float x){ return 1.f/(1.f+expf(-x)); }
__device__ __forceinline__ void astoref(float* p, float v){
  __hip_atomic_store(p, v, __ATOMIC_RELAXED, __HIP_MEMORY_SCOPE_AGENT);
}
__device__ __forceinline__ void astoreu64(u64* p, u64 v){
  __hip_atomic_store(p, v, __ATOMIC_RELAXED, __HIP_MEMORY_SCOPE_AGENT);
}
__device__ __forceinline__ u64 aloadu64(const u64* p){
  return __hip_atomic_load((u64*)p, __ATOMIC_RELAXED, __HIP_MEMORY_SCOPE_AGENT);
}
__device__ __forceinline__ uint aloadu32(const uint* p){
  return __hip_atomic_load((uint*)p, __ATOMIC_RELAXED, __HIP_MEMORY_SCOPE_AGENT);
}

// pack (score, slot) so that u64 max == (max value, min slot on ties) — matches lax.top_k
__device__ __forceinline__ u64 packsc(float v, int slot){
  uint u = __float_as_uint(v);
  u = (u & 0x80000000u) ? ~u : (u | 0x80000000u);
  return ((u64)u << 10) | (u64)(1023 - slot);
}
__device__ __forceinline__ float unpackval(u64 p){
  uint u = (uint)(p >> 10);
  uint bits = (u & 0x80000000u) ? (u & 0x7fffffffu) : ~u;
  return __uint_as_float(bits);
}
__device__ __forceinline__ int unpackslot(u64 p){ return 1023 - (int)(p & 1023u); }

// ---- split-phase gather/broadcast grid barrier ----
// arrv[0..127]: per-WG arrival gens (128B apart). arrv[128..143]: 16 bcast replicas.
// Generations are monotonic; flags zeroed by host memset before each launch.
__device__ __forceinline__ void b_arrive(uint* arrv, uint gen){
  asm volatile("s_waitcnt vmcnt(0)" ::: "memory");   // drain sc-stores (incl. asm) to coherence point
  __syncthreads();                                   // whole WG done with the phase
  if (threadIdx.x == 0)
    __hip_atomic_store(arrv + (size_t)blockIdx.x*32, gen, __ATOMIC_RELAXED, __HIP_MEMORY_SCOPE_AGENT);
}
__device__ __forceinline__ void b_wait(uint* arrv, uint gen){
  if (blockIdx.x == 0){
    if (threadIdx.x < NWG){
      while (aloadu32(arrv + (size_t)threadIdx.x*32) < gen)
        __builtin_amdgcn_s_sleep(1);
    }
    __syncthreads();
    if (threadIdx.x < 16)
      __hip_atomic_store(arrv + (size_t)(NWG + threadIdx.x)*32, gen, __ATOMIC_RELAXED, __HIP_MEMORY_SCOPE_AGENT);
    __syncthreads();
  } else {
    if (threadIdx.x == 0){
      while (aloadu32(arrv + (size_t)(NWG + (blockIdx.x & 15))*32) < gen)
        __builtin_amdgcn_s_sleep(1);
    }
    __syncthreads();
  }
}

// ---------------- phase 0a: embedding gather ----------------
__global__ __launch_bounds__(256) void prep_emb(const float* __restrict__ E,
                                                const int* __restrict__ seq,
                                                float* __restrict__ EMB){
  int m = blockIdx.x;              // m = t*16 + b
  int t = m >> 4, b = m & 15;
  int x = seq[b*T_STEPS + t];
  EMB[(size_t)m*256 + threadIdx.x] = E[(size_t)x*256 + threadIdx.x];
}

// ---------------- phase 0b: G_emb[m][p] = EMB[m] . W_ih[r(p)][0:256] + b_ih[r]+b_hh[r] ----
// packed: p = u*4+g, r = g*512+u
__global__ __launch_bounds__(256) void gemm_emb(const float* __restrict__ A,
                                                const float* __restrict__ W_ih,
                                                const float* __restrict__ b_ih,
                                                const float* __restrict__ b_hh,
                                                float* __restrict__ C){
  __shared__ __align__(16) float As[16*68];
  __shared__ __align__(16) float Bs[16*68];
  int mt = blockIdx.x & 31, nt = blockIdx.x >> 5;
  int m0 = mt*64, n0 = nt*64;
  int tx = threadIdx.x & 15, ty = threadIdx.x >> 4;
  float acc[4][4] = {};
  for (int k0 = 0; k0 < 256; k0 += 16){
    int mm = threadIdx.x >> 2, kq = (threadIdx.x & 3)*4;
    float4 a = *(const float4*)(A + (size_t)(m0+mm)*256 + k0 + kq);
    As[(kq+0)*68+mm]=a.x; As[(kq+1)*68+mm]=a.y; As[(kq+2)*68+mm]=a.z; As[(kq+3)*68+mm]=a.w;
    int pp = n0 + mm;
    int r = (pp & 3)*512 + (pp >> 2);
    float4 bv = *(const float4*)(W_ih + (size_t)r*320 + k0 + kq);
    Bs[(kq+0)*68+mm]=bv.x; Bs[(kq+1)*68+mm]=bv.y; Bs[(kq+2)*68+mm]=bv.z; Bs[(kq+3)*68+mm]=bv.w;
    __syncthreads();
    #pragma unroll
    for (int kk = 0; kk < 16; ++kk){
      float4 av = *(const float4*)(As + kk*68 + ty*4);
      float4 bb = *(const float4*)(Bs + kk*68 + tx*4);
      float aa[4] = {av.x,av.y,av.z,av.w};
      float bv2[4] = {bb.x,bb.y,bb.z,bb.w};
      #pragma unroll
      for (int i = 0; i < 4; ++i)
        #pragma unroll
        for (int j = 0; j < 4; ++j)
          acc[i][j] = fmaf(aa[i], bv2[j], acc[i][j]);
    }
    __syncthreads();
  }
  #pragma unroll
  for (int i = 0; i < 4; ++i){
    int m = m0 + ty*4 + i;
    #pragma unroll
    for (int j = 0; j < 4; ++j){
      int pp = n0 + tx*4 + j;
      int r = (pp & 3)*512 + (pp >> 2);
      C[(size_t)m*2048 + pp] = acc[i][j] + b_ih[r] + b_hh[r];
    }
  }
}

// ---------------- the sequential recurrence (128 WGs x 256, split-phase barriers) ----------------
__global__ __launch_bounds__(256, 1) void recurrent_kernel(
    const float* __restrict__ W_hh, const float* __restrict__ W_ih,
    const float* __restrict__ W_rk, const float* __restrict__ b_rk,
    const float* __restrict__ W_wk, const float* __restrict__ b_wk,
    const float* __restrict__ W_wv, const float* __restrict__ b_wv,
    const float* __restrict__ W_er, const float* __restrict__ b_er,
    const float* __restrict__ G_emb, float* __restrict__ H_all,
    float* __restrict__ mem_g, float* __restrict__ projbuf,
    float* __restrict__ rv_g, u64* __restrict__ cand,
    u64* __restrict__ wlist, uint* __restrict__ arrv)
{
  __shared__ __align__(16) float smem[L_TOT];
  float* mem_s  = smem + L_MEM;
  float* nrm_s  = smem + L_NRM;
  float* Ws     = smem + L_WS;
  float* hs     = smem + L_HS;
  float* key_s  = smem + L_KEY;
  float* knrm_s = smem + L_KNRM;
  float* sc_s   = smem + L_SC;
  float* wv_s   = smem + L_WV;
  float* er_s   = smem + L_ER;
  u64*   wl_s   = (u64*)(smem + L_WL);
  float* gl     = smem + L_GL;
  float* rv_st  = smem + L_RV;

  const int tid = threadIdx.x;
  const int wg  = blockIdx.x;
  float c_reg = 0.f;

  // gate role: thread owns (batch p1_b, packed gate col pcol)
  const int p1_b = tid >> 4, p1_col = tid & 15;
  const int pcol = wg*16 + p1_col;
  const int rrow = (pcol & 3)*512 + (pcol >> 2);
  // proj role
  const int msel = wg >> 5;
  const int col0 = (wg & 31)*8;
  const float* Wm  = (msel==0)? W_rk : (msel==1)? W_wk : (msel==2)? W_wv : W_er;
  const float* bmp = (msel==0)? b_rk : (msel==1)? b_wk : (msel==2)? b_wv : b_er;
  // P3 role: memory slot range
  const int bb3 = wg >> 3, rg = wg & 7, s0 = rg*128;
  float* mslice_g = mem_g + ((size_t)bb3*NSLOT + s0)*MD;

  // ======== prologue: stage Ws, init memory, h_0 = LSTM(G_emb[0]) ========
  for (int i = tid; i < 8*HID; i += 256){
    int k = i >> 3, j = i & 7;
    Ws[j*516 + k] = Wm[(size_t)k*256 + col0 + j];
  }
  for (int i = tid; i < 128*MD; i += 256){
    mem_s[(i >> 6)*68 + (i & 63)] = 1e-6f;
    astoref(mslice_g + i, 1e-6f);
  }
  gl[p1_b*16 + p1_col] = G_emb[(size_t)p1_b*2048 + pcol];
  __syncthreads();
  if (p1_col < 4){
    float gi = gl[p1_b*16 + p1_col*4 + 0];
    float gf = gl[p1_b*16 + p1_col*4 + 1];
    float gg = gl[p1_b*16 + p1_col*4 + 2];
    float go = gl[p1_b*16 + p1_col*4 + 3];
    c_reg = sigm(gf)*c_reg + sigm(gi)*tanhf(gg);
    float h = sigm(go)*tanhf(c_reg);
    astoref(H_all + (size_t)p1_b*HID + wg*4 + p1_col, h);
  }
  b_arrive(arrv, 1);

  #pragma clang loop unroll(disable)
  for (int t = 0; t < T_STEPS-1; ++t){
    const uint g0 = (uint)(4*t);
    b_wait(arrv, g0 + 1);                 // h_t visible

    // ======== P2: stage h_t; proj rk|wk|wv|er (WG owns 8 cols x 16 batches) ========
    {
      const float4* hsrc = (const float4*)(H_all + (size_t)t*BQ*HID);
      for (int i = tid; i < BQ*HID/4; i += 256){   // fresh addresses: normal loads OK
        int b = i >> 7, q = i & 127;
        *(float4*)(hs + b*516 + q*4) = hsrc[i];
      }
      __syncthreads();
      int b = tid >> 4, o2 = (tid & 15) >> 1, half = tid & 1;
      const float4* wp = (const float4*)(Ws + o2*516 + half*256);
      const float4* xp = (const float4*)(hs + b*516 + half*256);
      float a0 = 0.f, a1 = 0.f;
      #pragma unroll 4
      for (int k = 0; k < 64; k += 2){
        float4 w = wp[k], x = xp[k];
        a0=fmaf(w.x,x.x,a0); a0=fmaf(w.y,x.y,a0); a0=fmaf(w.z,x.z,a0); a0=fmaf(w.w,x.w,a0);
        w = wp[k+1]; x = xp[k+1];
        a1=fmaf(w.x,x.x,a1); a1=fmaf(w.y,x.y,a1); a1=fmaf(w.z,x.z,a1); a1=fmaf(w.w,x.w,a1);
      }
      float acc = a0 + a1;
      float other = __shfl_xor(acc, 1);
      if (half == 0){
        float v = acc + other + bmp[col0 + o2];
        if (msel == 3) v = sigm(v);
        astoref(projbuf + (size_t)(t&1)*BQ*1024 + (size_t)b*1024 + msel*256 + col0 + o2, v);
      }
    }
    b_arrive(arrv, g0 + 2);

    // ======== overlap slot (hidden under B2): deferred mem update + norms + g_part ========
    float gp;
    {
      const int parp = (t & 1) ^ 1;
      if (t > 0){
        const float* projp = projbuf + (size_t)parp*BQ*1024 + (size_t)bb3*1024;
        if (tid < 32)
          wl_s[tid] = aloadu64(wlist + (size_t)bb3*32 + tid);
        if (tid < 64){
          float4 v; AL4(v, (const float4*)(projp + 512) + tid); AWAIT();
          *(float4*)(wv_s + tid*4) = v;
        } else if (tid < 128){
          int i = tid - 64;
          float4 v; AL4(v, (const float4*)(projp + 768) + i); AWAIT();
          *(float4*)(er_s + i*4) = v;
        }
      }
      __syncthreads();
      if (t > 0 && tid < 64){
        const int d = tid;
        #pragma unroll 1
        for (int e = 0; e < 32; ++e){        // erases first (keep = prod over heads)
          u64 w64 = wl_s[e];
          int sl = (int)(w64 & 0xffffffffu);
          if (sl >= s0 && sl < s0+128){
            float w = __uint_as_float((uint)(w64 >> 32));
            mem_s[(sl-s0)*68 + d] *= (1.f - w*er_s[(e >> 3)*64 + d]);
          }
        }
        #pragma unroll 1
        for (int e = 0; e < 32; ++e){        // then adds
          u64 w64 = wl_s[e];
          int sl = (int)(w64 & 0xffffffffu);
          if (sl >= s0 && sl < s0+128){
            float w = __uint_as_float((uint)(w64 >> 32));
            mem_s[(sl-s0)*68 + d] += w*wv_s[(e >> 3)*64 + d];
          }
        }
        #pragma unroll 1
        for (int e = 0; e < 32; ++e){        // mirror changed rows for P4's gather
          u64 w64 = wl_s[e];
          int sl = (int)(w64 & 0xffffffffu);
          if (sl >= s0 && sl < s0+128)
            astoref(mslice_g + (sl-s0)*MD + d, mem_s[(sl-s0)*68 + d]);
        }
      }
      __syncthreads();
      {  // slot norms (post-update)
        int s = tid >> 1, half = tid & 1;
        const float4* mp = (const float4*)(mem_s + s*68 + half*32);
        float sum = 0.f;
        #pragma unroll
        for (int q = 0; q < 8; ++q){
          float4 v = mp[q];
          sum = fmaf(v.x,v.x,sum); sum = fmaf(v.y,v.y,sum);
          sum = fmaf(v.z,v.z,sum); sum = fmaf(v.w,v.w,sum);
        }
        sum += __shfl_xor(sum, 1);
        if (half == 0) nrm_s[s] = sqrtf(sum) + EPSN;
      }
      {  // g_part(t+1) = G_emb[t+1] + h_t @ W_hh (the 512-deep part)
        float a0 = G_emb[(size_t)((t+1)*BQ + p1_b)*2048 + pcol];
        float a1 = 0.f, a2 = 0.f, a3 = 0.f;
        const float4* wh = (const float4*)(W_hh + (size_t)rrow*HID);
        const float4* xv = (const float4*)(hs + p1_b*516);
        #pragma unroll 2
        for (int k = 0; k < 128; k += 4){
          float4 w, x;
          w=wh[k+0]; x=xv[k+0]; a0=fmaf(w.x,x.x,a0); a0=fmaf(w.y,x.y,a0); a0=fmaf(w.z,x.z,a0); a0=fmaf(w.w,x.w,a0);
          w=wh[k+1]; x=xv[k+1]; a1=fmaf(w.x,x.x,a1); a1=fmaf(w.y,x.y,a1); a1=fmaf(w.z,x.z,a1); a1=fmaf(w.w,x.w,a1);
          w=wh[k+2]; x=xv[k+2]; a2=fmaf(w.x,x.x,a2); a2=fmaf(w.y,x.y,a2); a2=fmaf(w.z,x.z,a2); a2=fmaf(w.w,x.w,a2);
          w=wh[k+3]; x=xv[k+3]; a3=fmaf(w.x,x.x,a3); a3=fmaf(w.y,x.y,a3); a3=fmaf(w.w,x.w,a3); a3=fmaf(w.z,x.z,a3);
        }
        gp = (a0+a1)+(a2+a3);
      }
    }
    b_wait(arrv, g0 + 2);                 // keys visible

    // ======== P3: scores + local top8 for own 128-slot range ========
    {
      const float* projb = projbuf + (size_t)(t&1)*BQ*1024 + (size_t)bb3*1024;
      if (tid < 128){
        float4 kv; AL4(kv, (const float4*)projb + tid); AWAIT();
        *(float4*)(key_s + tid*4) = kv;
      }
      __syncthreads();
      if (tid < 8){
        const float4* kp = (const float4*)(key_s + tid*MD);
        float sum = 0.f;
        #pragma unroll
        for (int q = 0; q < 16; ++q){
          float4 v = kp[q];
          sum = fmaf(v.x,v.x,sum); sum = fmaf(v.y,v.y,sum);
          sum = fmaf(v.z,v.z,sum); sum = fmaf(v.w,v.w,sum);
        }
        knrm_s[tid] = sqrtf(sum) + EPSN;
      }
      __syncthreads();
      {
        int s = tid >> 1, kh = tid & 1;
        const float4* mp = (const float4*)(mem_s + s*68);
        float rnm = 1.f / nrm_s[s];
        float acc4[4] = {0.f,0.f,0.f,0.f};
        #pragma unroll
        for (int q = 0; q < 16; ++q){
          float4 m = mp[q];
          #pragma unroll
          for (int kk = 0; kk < 4; ++kk){
            float4 k4 = *(const float4*)(key_s + (kh*4+kk)*MD + q*4);
            acc4[kk] = fmaf(m.x,k4.x,acc4[kk]); acc4[kk] = fmaf(m.y,k4.y,acc4[kk]);
            acc4[kk] = fmaf(m.z,k4.z,acc4[kk]); acc4[kk] = fmaf(m.w,k4.w,acc4[kk]);
          }
        }
        #pragma unroll
        for (int kk = 0; kk < 4; ++kk){
          int key = kh*4 + kk;
          sc_s[key*128 + s] = BETA * acc4[kk] * rnm / knrm_s[key];
        }
      }
      __syncthreads();
      {
        int wid = tid >> 6, lane = tid & 63;
        #pragma unroll
        for (int kk = 0; kk < 2; ++kk){
          int key = wid*2 + kk;
          u64 p0 = packsc(sc_s[key*128 + lane],      s0 + lane);
          u64 p1 = packsc(sc_s[key*128 + 64 + lane], s0 + 64 + lane);
          #pragma unroll
          for (int r = 0; r < 8; ++r){
            u64 m = p0 > p1 ? p0 : p1;
            #pragma unroll
            for (int o = 32; o; o >>= 1){ u64 q = __shfl_xor(m, o); if (q > m) m = q; }
            if (p0 == m) p0 = 0; else if (p1 == m) p1 = 0;
            if (lane == 0) astoreu64(cand + (((size_t)bb3*8 + key)*8 + rg)*8 + r, m);
          }
        }
      }
    }
    b_arrive(arrv, g0 + 3);
    b_wait(arrv, g0 + 3);                 // candidates + mirrored rows visible

    // ======== P4: merge top8, softmax, read_vec, write-lists (WG b < 16) ========
    if (wg < BQ){
      const int bb = wg;
      int wid = tid >> 6, lane = tid & 63;
      #pragma unroll
      for (int kk = 0; kk < 2; ++kk){
        int key = wid*2 + kk;
        u64 pv = aloadu64(cand + (((size_t)bb*8 + key)*8 + (lane >> 3))*8 + (lane & 7));
        u64 sel = 0;
        #pragma unroll
        for (int r = 0; r < 8; ++r){
          u64 m = pv;
          #pragma unroll
          for (int o = 32; o; o >>= 1){ u64 q = __shfl_xor(m, o); if (q > m) m = q; }
          if (pv == m) pv = 0;
          if (lane == r) sel = m;
        }
        float val = unpackval(sel);
        int slot = unpackslot(sel);
        float vmax = __shfl(val, 0);
        float e = (lane < 8) ? expf(val - vmax) : 0.f;
        float ssum = e;
        #pragma unroll
        for (int o = 32; o; o >>= 1) ssum += __shfl_xor(ssum, o);
        float w = e / ssum;
        if (key < 4){
          int sls[8];
          #pragma unroll
          for (int i = 0; i < 8; ++i) sls[i] = __shfl(slot, i);
          float mv[8];
          #pragma unroll
          for (int i = 0; i < 8; ++i)
            ALF(mv[i], mem_g + ((size_t)bb*NSLOT + sls[i])*MD + lane);
          AWAIT();
          float acc = 0.f;
          #pragma unroll
          for (int i = 0; i < 8; ++i) acc = fmaf(__shfl(w, i), mv[i], acc);
          rv_st[key*64 + lane] = acc;     // scratch reuse: partial per head
        } else if (lane < 8){
          astoreu64(wlist + (size_t)bb*32 + (key-4)*8 + lane,
                    ((u64)__float_as_uint(w) << 32) | (u64)(uint)slot);
        }
      }
      __syncthreads();
      if (tid < 64){
        float m = 0.25f*(rv_st[tid] + rv_st[64+tid] + rv_st[128+tid] + rv_st[192+tid]);
        astoref(rv_g + (size_t)bb*MD + tid, m);
      }
    }
    b_arrive(arrv, g0 + 4);
    b_wait(arrv, g0 + 4);                 // rv + write-lists visible

    // ======== finish: gates = g_part + rv@W_rv; LSTM; publish h_{t+1} ========
    {
      float4 rvv; AL4(rvv, (const float4*)rv_g + tid); AWAIT();
      *(float4*)(rv_st + tid*4) = rvv;
      __syncthreads();
      float a0 = gp, a1 = 0.f;
      const float4* wi = (const float4*)(W_ih + (size_t)rrow*320 + 256);
      const float4* xr = (const float4*)(rv_st + p1_b*64);
      #pragma unroll
      for (int k = 0; k < 16; k += 2){
        float4 w = wi[k], x = xr[k];
        a0=fmaf(w.x,x.x,a0); a0=fmaf(w.y,x.y,a0); a0=fmaf(w.z,x.z,a0); a0=fmaf(w.w,x.w,a0);
        w = wi[k+1]; x = xr[k+1];
        a1=fmaf(w.x,x.x,a1); a1=fmaf(w.y,x.y,a1); a1=fmaf(w.z,x.z,a1); a1=fmaf(w.w,x.w,a1);
      }
      gl[p1_b*16 + p1_col] = a0 + a1;
      __syncthreads();
      if (p1_col < 4){
        float gi = gl[p1_b*16 + p1_col*4 + 0];
        float gf = gl[p1_b*16 + p1_col*4 + 1];
        float gg = gl[p1_b*16 + p1_col*4 + 2];
        float go = gl[p1_b*16 + p1_col*4 + 3];
        c_reg = sigm(gf)*c_reg + sigm(gi)*tanhf(gg);
        float h = sigm(go)*tanhf(c_reg);
        astoref(H_all + (size_t)((t+1)*BQ + p1_b)*HID + wg*4 + p1_col, h);
      }
    }
    b_arrive(arrv, g0 + 5);
  }
}

// ---------------- phase B: logits = H_all[2048,512] @ W_out[512,32000] + b_out ----------------
__global__ __launch_bounds__(256) void gemm_out(const float* __restrict__ A,
                                                const float* __restrict__ Bmat,
                                                const float* __restrict__ bias,
                                                float* __restrict__ C){
  __shared__ __align__(16) float As[16*132];
  __shared__ __align__(16) float Bs[16*64];
  int mt = blockIdx.x & 15, nt = blockIdx.x >> 4;
  int m0 = mt*128, n0 = nt*64;
  int tx = threadIdx.x & 15, ty = threadIdx.x >> 4;
  float acc[8][4] = {};
  for (int k0 = 0; k0 < 512; k0 += 16){
    int mm = threadIdx.x >> 1, kq = (threadIdx.x & 1)*8;
    float4 a0 = *(const float4*)(A + (size_t)(m0+mm)*512 + k0 + kq);
    float4 a1 = *(const float4*)(A + (size_t)(m0+mm)*512 + k0 + kq + 4);
    As[(kq+0)*132+mm]=a0.x; As[(kq+1)*132+mm]=a0.y; As[(kq+2)*132+mm]=a0.z; As[(kq+3)*132+mm]=a0.w;
    As[(kq+4)*132+mm]=a1.x; As[(kq+5)*132+mm]=a1.y; As[(kq+6)*132+mm]=a1.z; As[(kq+7)*132+mm]=a1.w;
    int kk2 = threadIdx.x >> 4, nq = (threadIdx.x & 15)*4;
    *(float4*)(Bs + kk2*64 + nq) = *(const float4*)(Bmat + (size_t)(k0+kk2)*VOCAB + n0 + nq);
    __syncthreads();
    #pragma unroll
    for (int kk = 0; kk < 16; ++kk){
      float4 x0 = *(const float4*)(As + kk*132 + ty*8);
      float4 x1 = *(const float4*)(As + kk*132 + ty*8 + 4);
      float4 bv = *(const float4*)(Bs + kk*64 + tx*4);
      float aa[8] = {x0.x,x0.y,x0.z,x0.w,x1.x,x1.y,x1.z,x1.w};
      float bb[4] = {bv.x,bv.y,bv.z,bv.w};
      #pragma unroll
      for (int i = 0; i < 8; ++i)
        #pragma unroll
        for (int j = 0; j < 4; ++j)
          acc[i][j] = fmaf(aa[i], bb[j], acc[i][j]);
    }
    __syncthreads();
  }
  #pragma unroll
  for (int i = 0; i < 8; ++i){
    int m = m0 + ty*8 + i;
    int bq = m & 15, tt = m >> 4;
    float* crow = C + ((size_t)bq*T_STEPS + tt)*VOCAB + n0 + tx*4;
    #pragma unroll
    for (int j = 0; j < 4; ++j) crow[j] = acc[i][j] + bias[n0 + tx*4 + j];
  }
}

extern "C" void kernel_launch(void* const* d_in, const int* in_sizes, int n_in,
                              void* d_out, int out_size, void* d_ws, size_t ws_size,
                              hipStream_t stream){
  const int*   seq   = (const int*)d_in[0];
  const float* E     = (const float*)d_in[1];
  const float* W_ih  = (const float*)d_in[2];
  const float* W_hh  = (const float*)d_in[3];
  const float* b_ih  = (const float*)d_in[4];
  const float* b_hh  = (const float*)d_in[5];
  const float* W_out = (const float*)d_in[6];
  const float* b_out = (const float*)d_in[7];
  const float* W_rk  = (const float*)d_in[8];
  const float* b_rk  = (const float*)d_in[9];
  const float* W_wk  = (const float*)d_in[10];
  const float* b_wk  = (const float*)d_in[11];
  const float* W_wv  = (const float*)d_in[12];
  const float* b_wv  = (const float*)d_in[13];
  const float* W_er  = (const float*)d_in[14];
  const float* b_er  = (const float*)d_in[15];
  float* out = (float*)d_out;
  (void)in_sizes; (void)n_in; (void)out_size; (void)ws_size;

  char* ws = (char*)d_ws;
  size_t off = 0;
  auto alloc = [&](size_t bytes) -> void* {
    off = (off + 255) & ~(size_t)255;
    void* p = ws + off;
    off += bytes;
    return p;
  };
  float* EMB     = (float*)alloc((size_t)2048*256*4);
  float* G_emb   = (float*)alloc((size_t)2048*2048*4);
  float* H_all   = (float*)alloc((size_t)2048*512*4);
  float* memb    = (float*)alloc((size_t)16*1024*64*4);
  float* projbuf = (float*)alloc((size_t)2*16*1024*4);
  float* rv_g    = (float*)alloc((size_t)16*64*4);
  u64*   cand    = (u64*)alloc((size_t)16*8*8*8*8);
  u64*   wlist   = (u64*)alloc((size_t)16*32*8);
  uint*  arrv    = (uint*)alloc((size_t)(NWG+16)*32*4);

  hipMemsetAsync(arrv, 0, (size_t)(NWG+16)*32*4, stream);   // flags zero each replay
  prep_emb<<<2048, 256, 0, stream>>>(E, seq, EMB);
  gemm_emb<<<1024, 256, 0, stream>>>(EMB, W_ih, b_ih, b_hh, G_emb);
  recurrent_kernel<<<NWG, 256, 0, stream>>>(W_hh, W_ih, W_rk, b_rk, W_wk, b_wk,
                                            W_wv, b_wv, W_er, b_er,
                                            G_emb, H_all, memb, projbuf, rv_g,
                                            cand, wlist, arrv);
  gemm_out<<<16*500, 256, 0, stream>>>(H_all, W_out, b_out, out);
}